// Round 13
// baseline (26.810 us; speedup 1.0000x reference)
//
#include <hip/hip_runtime.h>
#include <math.h>

#define BATCH 32
#define H 512
#define W 512
#define PAD 15
#define BAND 8                        /* rows per block */
#define NBANDS (H / BAND)             /* 64 */
#define NBLOCKS (BATCH * NBANDS)      /* 2048 */
#define NXCD 8
#define INV_KK (1.0f / 961.0f)

/* ---------- fused weight + stable BCE for one element (verified R8) ------ */
#define EMIT(tv, lv, hs)                                                      \
    {                                                                         \
        float pooled_ = (hs) * INV_KK;                                        \
        float wgt_ = fmaf(5.f, fabsf(pooled_ - (tv)), 1.f);                   \
        float al_ = fabsf(lv);                                                \
        float bce_ = fmaxf((lv), 0.f) - (lv) * (tv)                           \
                     + __logf(1.f + __expf(-al_));                            \
        num = fmaf(wgt_, bce_, num);                                          \
        den += wgt_;                                                          \
    }

/* one k-slot of the horizontal 31-window (verified bit-exact R7..R12) */
#define KSLOT(pk, pkm1, tv, lv, FIRST, LAST)                                  \
    {                                                                         \
        float hs_ = base_;                                                    \
        if (!(LAST)) {                                                        \
            float sa_ = __shfl_up(tot_ - (pk), 2);                            \
            hs_ += okm2 ? sa_ : 0.f;                                          \
        }                                                                     \
        if (!(FIRST)) {                                                       \
            float se_ = __shfl_down((pkm1), 2);                               \
            hs_ += okp2 ? se_ : 0.f;                                          \
        }                                                                     \
        EMIT(tv, lv, hs_)                                                     \
    }

#define ROW_EMIT(va, vb, t0_, t1_, l0_, l1_)                                  \
    {                                                                         \
        const float p0_ = (va).x;                                             \
        const float p1_ = p0_ + (va).y;                                       \
        const float p2_ = p1_ + (va).z;                                       \
        const float p3_ = p2_ + (va).w;                                       \
        const float p4_ = p3_ + (vb).x;                                       \
        const float p5_ = p4_ + (vb).y;                                       \
        const float p6_ = p5_ + (vb).z;                                       \
        const float tot_ = p6_ + (vb).w;                                      \
        const float bm_ = __shfl_up(tot_, 1);                                 \
        const float dp_ = __shfl_down(tot_, 1);                               \
        const float base_ = (okm1 ? bm_ : 0.f) + tot_ + (okp1 ? dp_ : 0.f);   \
        KSLOT(p0_, 0.f, (t0_).x, (l0_).x, 1, 0)                               \
        KSLOT(p1_, p0_, (t0_).y, (l0_).y, 0, 0)                               \
        KSLOT(p2_, p1_, (t0_).z, (l0_).z, 0, 0)                               \
        KSLOT(p3_, p2_, (t0_).w, (l0_).w, 0, 0)                               \
        KSLOT(p4_, p3_, (t1_).x, (l1_).x, 0, 0)                               \
        KSLOT(p5_, p4_, (t1_).y, (l1_).y, 0, 0)                               \
        KSLOT(p6_, p5_, (t1_).z, (l1_).z, 0, 0)                               \
        KSLOT(0.f, p6_, (t1_).w, (l1_).w, 0, 1)                               \
    }

#define LDG(pa, pb, ptr, yy)                                                  \
    { const float4* p_ = (const float4*)((ptr) + (size_t)(yy) * W + x0);      \
      pa = p_[0]; pb = p_[1]; }

/* ---------- Phase 1: single-pass prefix-register vertical windows -------- */
/* thread owns adjacent columns 2*tid, 2*tid+1 (float2 loads).
   Stream 38 rows once (c=0..37, y=y0+c-15); run = cumsum; save prefixes
   pf0..pf6 (after c=0..6); when c==30+j emit vs[j] = run - pf[j-1]. */
#define P1ROW(G, c)                                                           \
    {                                                                         \
        const int y = y0 + (c) - PAD;                                         \
        float2 a = make_float2(0.f, 0.f);                                     \
        if ((G) || ((unsigned)y < (unsigned)H))                               \
            a = *(const float2*)(tb + (size_t)y * W + col2);                  \
        run.x += a.x; run.y += a.y;                                           \
        if ((c) == 0) pf0 = run;                                              \
        if ((c) == 1) pf1 = run;                                              \
        if ((c) == 2) pf2 = run;                                              \
        if ((c) == 3) pf3 = run;                                              \
        if ((c) == 4) pf4 = run;                                              \
        if ((c) == 5) pf5 = run;                                              \
        if ((c) == 6) pf6 = run;                                              \
        if ((c) >= 30) {                                                      \
            float2 v = run;                                                   \
            if ((c) == 31) { v.x -= pf0.x; v.y -= pf0.y; }                    \
            if ((c) == 32) { v.x -= pf1.x; v.y -= pf1.y; }                    \
            if ((c) == 33) { v.x -= pf2.x; v.y -= pf2.y; }                    \
            if ((c) == 34) { v.x -= pf3.x; v.y -= pf3.y; }                    \
            if ((c) == 35) { v.x -= pf4.x; v.y -= pf4.y; }                    \
            if ((c) == 36) { v.x -= pf5.x; v.y -= pf5.y; }                    \
            if ((c) == 37) { v.x -= pf6.x; v.y -= pf6.y; }                    \
            ((float2*)vs[(c) - 30])[tid] = v;                                 \
        }                                                                     \
    }

#define P1CHUNK(G, C0, C1)                                                    \
    _Pragma("unroll")                                                         \
    for (int c = (C0); c < (C1); ++c) P1ROW(G, c)

#define PHASE1(G)                                                             \
    P1CHUNK(G, 0, 8)   __builtin_amdgcn_sched_barrier(0);                     \
    P1CHUNK(G, 8, 16)  __builtin_amdgcn_sched_barrier(0);                     \
    P1CHUNK(G, 16, 24) __builtin_amdgcn_sched_barrier(0);                     \
    P1CHUNK(G, 24, 31) __builtin_amdgcn_sched_barrier(0);                     \
    P1CHUNK(G, 31, 38)

__global__ __launch_bounds__(256)
void wbce_band_kernel(const float* __restrict__ logits,
                      const float* __restrict__ targets,
                      float* __restrict__ partials) {
    __shared__ __align__(16) float vs[BAND][W];   /* 16 KB */
    __shared__ float rn[4], rd[4];

    const int tid  = threadIdx.x;
    const int lane = tid & 63;
    const int w    = tid >> 6;

    /* XCD-aware bijective swizzle: 256 consecutive blocks (4 images) per XCD */
    const int bid  = (int)blockIdx.x;
    const int sbid = (bid & (NXCD - 1)) * (NBLOCKS / NXCD) + (bid >> 3);

    const int img  = sbid >> 6;            /* sbid / NBANDS */
    const int band = sbid & (NBANDS - 1);
    const int y0   = band * BAND;
    const int x0   = lane * 8;
    const int col2 = tid * 2;

    const float* tb = targets + (size_t)img * H * W;
    const float* lb = logits  + (size_t)img * H * W;

    /* ---- Phase 2 prefetch (independent of Phase 1): wave = 2 rows ---- */
    const int jw = w * 2;
    float4 T0a, T0b, T1a, T1b, L0a, L0b, L1a, L1b;
    LDG(T0a, T0b, tb, y0 + jw + 0) LDG(L0a, L0b, lb, y0 + jw + 0)
    LDG(T1a, T1b, tb, y0 + jw + 1) LDG(L1a, L1b, lb, y0 + jw + 1)
    __builtin_amdgcn_sched_barrier(0);

    /* ---- Phase 1: cooperative vertical 31-row windows -> LDS ---- */
    float2 run = make_float2(0.f, 0.f);
    float2 pf0, pf1, pf2, pf3, pf4, pf5, pf6;
    if (y0 >= PAD && y0 + BAND + PAD - 1 < H) {
        PHASE1(1)
    } else {
        PHASE1(0)
    }
    __syncthreads();

    /* ---- Phase 2: horizontal window + fused weight/BCE ---- */
    const bool okm2 = lane >= 2, okm1 = lane >= 1;
    const bool okp1 = lane <= 62, okp2 = lane <= 61;
    float num = 0.f, den = 0.f;

    {
        float4 A0 = ((const float4*)vs[jw + 0])[2 * lane];
        float4 B0 = ((const float4*)vs[jw + 0])[2 * lane + 1];
        float4 A1 = ((const float4*)vs[jw + 1])[2 * lane];
        float4 B1 = ((const float4*)vs[jw + 1])[2 * lane + 1];
        ROW_EMIT(A0, B0, T0a, T0b, L0a, L0b)
        ROW_EMIT(A1, B1, T1a, T1b, L1a, L1b)
    }

    /* ---- wave + block reduction, one partial pair per block ---- */
    #pragma unroll
    for (int off = 32; off > 0; off >>= 1) {
        num += __shfl_down(num, off);
        den += __shfl_down(den, off);
    }
    if (lane == 0) { rn[w] = num; rd[w] = den; }
    __syncthreads();
    if (tid == 0) {
        float n = 0.f, d = 0.f;
        #pragma unroll
        for (int i = 0; i < 4; ++i) { n += rn[i]; d += rd[i]; }
        partials[sbid * 2]     = n;
        partials[sbid * 2 + 1] = d;
    }
}

/* 2048 partial pairs -> scalar. Image i owns pairs [i*64, i*64+64). */
__global__ __launch_bounds__(1024)
void wbce_finalize_kernel(const float* __restrict__ partials,
                          float* __restrict__ out) {
    __shared__ float rsum[16];
    const int t = threadIdx.x;
    const int img = t >> 5;
    const int j = t & 31;
    const int base = img * NBANDS;
    float num = partials[(base + j) * 2]     + partials[(base + 32 + j) * 2];
    float den = partials[(base + j) * 2 + 1] + partials[(base + 32 + j) * 2 + 1];
    #pragma unroll
    for (int off = 16; off > 0; off >>= 1) {
        num += __shfl_down(num, off, 32);
        den += __shfl_down(den, off, 32);
    }
    float ratio = 0.f;
    if ((t & 31) == 0) ratio = num / den;
    ratio += __shfl_down(ratio, 32);          /* lane0 += lane32 */
    const int lane = t & 63;
    const int wv = t >> 6;
    if (lane == 0) rsum[wv] = ratio;
    __syncthreads();
    if (t == 0) {
        float s = 0.f;
        #pragma unroll
        for (int i = 0; i < 16; ++i) s += rsum[i];
        out[0] = s / (float)BATCH;
    }
}

extern "C" void kernel_launch(void* const* d_in, const int* in_sizes, int n_in,
                              void* d_out, int out_size, void* d_ws, size_t ws_size,
                              hipStream_t stream) {
    const float* logits  = (const float*)d_in[0];
    const float* targets = (const float*)d_in[1];
    float* out = (float*)d_out;
    float* partials = (float*)d_ws;   /* NBLOCKS*2 floats = 16 KB */

    wbce_band_kernel<<<NBLOCKS, 256, 0, stream>>>(logits, targets, partials);
    wbce_finalize_kernel<<<1, 1024, 0, stream>>>(partials, out);
}

// Round 14
// 26.441 us; speedup vs baseline: 1.0139x; 1.0139x over previous
//
#include <hip/hip_runtime.h>
#include <math.h>

#define BATCH 32
#define H 512
#define W 512
#define PAD 15
#define BAND 8                        /* rows per block */
#define NBANDS (H / BAND)             /* 64 */
#define NBLOCKS (BATCH * NBANDS)      /* 2048 */
#define NXCD 8
#define INV_KK (1.0f / 961.0f)

/* ---------- fused weight + stable BCE for one element (verified R8) ------ */
#define EMIT(tv, lv, hs)                                                      \
    {                                                                         \
        float pooled_ = (hs) * INV_KK;                                        \
        float wgt_ = fmaf(5.f, fabsf(pooled_ - (tv)), 1.f);                   \
        float al_ = fabsf(lv);                                                \
        float bce_ = fmaxf((lv), 0.f) - (lv) * (tv)                           \
                     + __logf(1.f + __expf(-al_));                            \
        num = fmaf(wgt_, bce_, num);                                          \
        den += wgt_;                                                          \
    }

/* one k-slot of the horizontal 31-window (verified bit-exact R7..R12) */
#define KSLOT(pk, pkm1, tv, lv, FIRST, LAST)                                  \
    {                                                                         \
        float hs_ = base_;                                                    \
        if (!(LAST)) {                                                        \
            float sa_ = __shfl_up(tot_ - (pk), 2);                            \
            hs_ += okm2 ? sa_ : 0.f;                                          \
        }                                                                     \
        if (!(FIRST)) {                                                       \
            float se_ = __shfl_down((pkm1), 2);                               \
            hs_ += okp2 ? se_ : 0.f;                                          \
        }                                                                     \
        EMIT(tv, lv, hs_)                                                     \
    }

#define LDG(pa, pb, ptr, yy)                                                  \
    { const float4* p_ = (const float4*)((ptr) + (size_t)(yy) * W + x0);      \
      pa = p_[0]; pb = p_[1]; }

/* full row: LDS vertical sums + t/l loads + horizontal window + BCE.
   Loads issued at row start; liveness ~40 floats. */
#define ROWPASS(r)                                                            \
    {                                                                         \
        float4 A_ = ((const float4*)vs[(r)])[2 * lane];                       \
        float4 B_ = ((const float4*)vs[(r)])[2 * lane + 1];                   \
        float4 Ta_, Tb_, La_, Lb_;                                            \
        LDG(Ta_, Tb_, tb, y0 + (r)) LDG(La_, Lb_, lb, y0 + (r))               \
        const float p0_ = A_.x;                                               \
        const float p1_ = p0_ + A_.y;                                         \
        const float p2_ = p1_ + A_.z;                                         \
        const float p3_ = p2_ + A_.w;                                         \
        const float p4_ = p3_ + B_.x;                                         \
        const float p5_ = p4_ + B_.y;                                         \
        const float p6_ = p5_ + B_.z;                                         \
        const float tot_ = p6_ + B_.w;                                        \
        const float bm_ = __shfl_up(tot_, 1);                                 \
        const float dp_ = __shfl_down(tot_, 1);                               \
        const float base_ = (okm1 ? bm_ : 0.f) + tot_ + (okp1 ? dp_ : 0.f);   \
        KSLOT(p0_, 0.f, Ta_.x, La_.x, 1, 0)                                   \
        KSLOT(p1_, p0_, Ta_.y, La_.y, 0, 0)                                   \
        KSLOT(p2_, p1_, Ta_.z, La_.z, 0, 0)                                   \
        KSLOT(p3_, p2_, Ta_.w, La_.w, 0, 0)                                   \
        KSLOT(p4_, p3_, Tb_.x, Lb_.x, 0, 0)                                   \
        KSLOT(p5_, p4_, Tb_.y, Lb_.y, 0, 0)                                   \
        KSLOT(p6_, p5_, Tb_.z, Lb_.z, 0, 0)                                   \
        KSLOT(0.f, p6_, Tb_.w, Lb_.w, 0, 1)                                   \
    }

/* ---------- Phase 1: vertical running windows into LDS (R12 champion) --- */
/* thread owns columns tid and tid+256; G=1 -> interior band, no guards     */
#define P1_INIT(G, C0, C1)                                                    \
    _Pragma("unroll")                                                         \
    for (int c = (C0); c < (C1); ++c) {                                       \
        const int y = y0 + c - PAD;                                           \
        float a0 = 0.f, a1 = 0.f;                                             \
        if ((G) || (unsigned)y < (unsigned)H) {                               \
            a0 = tcol[y * W]; a1 = tcol[y * W + 256];                         \
        }                                                                     \
        run0 += a0; run1 += a1;                                               \
    }

#define P1_SLIDE(G, J0, J1)                                                   \
    _Pragma("unroll")                                                         \
    for (int j = (J0); j < (J1); ++j) {                                       \
        vs[j][tid] = run0; vs[j][tid + 256] = run1;                           \
        if (j < BAND - 1) {                                                   \
            const int ye = y0 + j + PAD + 1, yl = y0 + j - PAD;               \
            float e0 = 0.f, e1 = 0.f, s0 = 0.f, s1 = 0.f;                     \
            if ((G) || (unsigned)ye < (unsigned)H) {                          \
                e0 = tcol[ye * W]; e1 = tcol[ye * W + 256];                   \
            }                                                                 \
            if ((G) || (unsigned)yl < (unsigned)H) {                          \
                s0 = tcol[yl * W]; s1 = tcol[yl * W + 256];                   \
            }                                                                 \
            run0 += e0 - s0; run1 += e1 - s1;                                 \
        }                                                                     \
    }

#define PHASE1(G)                                                             \
    P1_INIT(G, 0, 4)   __builtin_amdgcn_sched_barrier(0);                     \
    P1_INIT(G, 4, 8)   __builtin_amdgcn_sched_barrier(0);                     \
    P1_INIT(G, 8, 12)  __builtin_amdgcn_sched_barrier(0);                     \
    P1_INIT(G, 12, 16) __builtin_amdgcn_sched_barrier(0);                     \
    P1_INIT(G, 16, 20) __builtin_amdgcn_sched_barrier(0);                     \
    P1_INIT(G, 20, 24) __builtin_amdgcn_sched_barrier(0);                     \
    P1_INIT(G, 24, 28) __builtin_amdgcn_sched_barrier(0);                     \
    P1_INIT(G, 28, 31) __builtin_amdgcn_sched_barrier(0);                     \
    P1_SLIDE(G, 0, 4)  __builtin_amdgcn_sched_barrier(0);                     \
    P1_SLIDE(G, 4, 8)

__global__ __launch_bounds__(256)
__attribute__((amdgpu_waves_per_eu(8)))
void wbce_band_kernel(const float* __restrict__ logits,
                      const float* __restrict__ targets,
                      float* __restrict__ partials) {
    __shared__ __align__(16) float vs[BAND][W];   /* 16 KB */

    const int tid  = threadIdx.x;
    const int lane = tid & 63;
    const int w    = tid >> 6;

    /* XCD-aware bijective swizzle: 256 consecutive blocks (4 images) per XCD */
    const int bid  = (int)blockIdx.x;
    const int sbid = (bid & (NXCD - 1)) * (NBLOCKS / NXCD) + (bid >> 3);

    const int img  = sbid >> 6;            /* sbid / NBANDS */
    const int band = sbid & (NBANDS - 1);
    const int y0   = band * BAND;
    const int x0   = lane * 8;

    const float* tb = targets + (size_t)img * H * W;
    const float* lb = logits  + (size_t)img * H * W;
    const float* tcol = tb + tid;

    /* ---- Phase 1: cooperative vertical 31-row windows -> LDS ---- */
    float run0 = 0.f, run1 = 0.f;
    if (y0 >= PAD && y0 + BAND + PAD - 1 < H) {
        PHASE1(1)
    } else {
        PHASE1(0)
    }
    __syncthreads();

    /* ---- Phase 2: horizontal window + fused weight/BCE (wave = 2 rows) ---- */
    const bool okm2 = lane >= 2, okm1 = lane >= 1;
    const bool okp1 = lane <= 62, okp2 = lane <= 61;
    float num = 0.f, den = 0.f;

    const int jw = w * 2;
    ROWPASS(jw)
    ROWPASS(jw + 1)

    /* ---- wave reduction, one partial pair per wave ---- */
    #pragma unroll
    for (int off = 32; off > 0; off >>= 1) {
        num += __shfl_down(num, off);
        den += __shfl_down(den, off);
    }
    if (lane == 0) {
        const int wid = sbid * 4 + w;
        partials[wid * 2]     = num;
        partials[wid * 2 + 1] = den;
    }
}

/* 8192 partial pairs -> scalar. Image i owns pairs [i*256, i*256+256). */
__global__ __launch_bounds__(1024)
void wbce_finalize_kernel(const float* __restrict__ partials,
                          float* __restrict__ out) {
    __shared__ float rsum[16];
    const int t = threadIdx.x;
    const int img = t >> 5;
    const int j = t & 31;
    const int base = img * 256;
    float num = 0.f, den = 0.f;
    #pragma unroll
    for (int k = 0; k < 8; ++k) {
        num += partials[(base + j + 32 * k) * 2];
        den += partials[(base + j + 32 * k) * 2 + 1];
    }
    #pragma unroll
    for (int off = 16; off > 0; off >>= 1) {
        num += __shfl_down(num, off, 32);
        den += __shfl_down(den, off, 32);
    }
    float ratio = 0.f;
    if ((t & 31) == 0) ratio = num / den;
    ratio += __shfl_down(ratio, 32);          /* lane0 += lane32 */
    const int lane = t & 63;
    const int wv = t >> 6;
    if (lane == 0) rsum[wv] = ratio;
    __syncthreads();
    if (t == 0) {
        float s = 0.f;
        #pragma unroll
        for (int i = 0; i < 16; ++i) s += rsum[i];
        out[0] = s / (float)BATCH;
    }
}

extern "C" void kernel_launch(void* const* d_in, const int* in_sizes, int n_in,
                              void* d_out, int out_size, void* d_ws, size_t ws_size,
                              hipStream_t stream) {
    const float* logits  = (const float*)d_in[0];
    const float* targets = (const float*)d_in[1];
    float* out = (float*)d_out;
    float* partials = (float*)d_ws;   /* NBLOCKS*4*2 floats = 64 KB */

    wbce_band_kernel<<<NBLOCKS, 256, 0, stream>>>(logits, targets, partials);
    wbce_finalize_kernel<<<1, 1024, 0, stream>>>(partials, out);
}

// Round 15
// 25.179 us; speedup vs baseline: 1.0648x; 1.0501x over previous
//
#include <hip/hip_runtime.h>
#include <math.h>

#define BATCH 32
#define H 512
#define W 512
#define PAD 15
#define BAND 8                        /* rows per block */
#define NBANDS (H / BAND)             /* 64 */
#define NBLOCKS (BATCH * NBANDS)      /* 2048 */
#define NXCD 8
#define INV_KK (1.0f / 961.0f)

/* ---------- fused weight + stable BCE for one element (verified R8) ------ */
#define EMIT(tv, lv, hs)                                                      \
    {                                                                         \
        float pooled_ = (hs) * INV_KK;                                        \
        float wgt_ = fmaf(5.f, fabsf(pooled_ - (tv)), 1.f);                   \
        float al_ = fabsf(lv);                                                \
        float bce_ = fmaxf((lv), 0.f) - (lv) * (tv)                           \
                     + __logf(1.f + __expf(-al_));                            \
        num = fmaf(wgt_, bce_, num);                                          \
        den += wgt_;                                                          \
    }

/* one k-slot of the horizontal 31-window (verified bit-exact R7..R13) */
#define KSLOT(pk, pkm1, tv, lv, FIRST, LAST)                                  \
    {                                                                         \
        float hs_ = base_;                                                    \
        if (!(LAST)) {                                                        \
            float sa_ = __shfl_up(tot_ - (pk), 2);                            \
            hs_ += okm2 ? sa_ : 0.f;                                          \
        }                                                                     \
        if (!(FIRST)) {                                                       \
            float se_ = __shfl_down((pkm1), 2);                               \
            hs_ += okp2 ? se_ : 0.f;                                          \
        }                                                                     \
        EMIT(tv, lv, hs_)                                                     \
    }

#define LDG(pa, pb, ptr, yy)                                                  \
    { const float4* p_ = (const float4*)((ptr) + (size_t)(yy) * W + x0);      \
      pa = p_[0]; pb = p_[1]; }

/* full row: LDS vertical sums + t/l loads + horizontal window + BCE. */
#define ROWPASS(r)                                                            \
    {                                                                         \
        float4 A_ = ((const float4*)vs[(r)])[2 * lane];                       \
        float4 B_ = ((const float4*)vs[(r)])[2 * lane + 1];                   \
        float4 Ta_, Tb_, La_, Lb_;                                            \
        LDG(Ta_, Tb_, tb, y0 + (r)) LDG(La_, Lb_, lb, y0 + (r))               \
        const float p0_ = A_.x;                                               \
        const float p1_ = p0_ + A_.y;                                         \
        const float p2_ = p1_ + A_.z;                                         \
        const float p3_ = p2_ + A_.w;                                         \
        const float p4_ = p3_ + B_.x;                                         \
        const float p5_ = p4_ + B_.y;                                         \
        const float p6_ = p5_ + B_.z;                                         \
        const float tot_ = p6_ + B_.w;                                        \
        const float bm_ = __shfl_up(tot_, 1);                                 \
        const float dp_ = __shfl_down(tot_, 1);                               \
        const float base_ = (okm1 ? bm_ : 0.f) + tot_ + (okp1 ? dp_ : 0.f);   \
        KSLOT(p0_, 0.f, Ta_.x, La_.x, 1, 0)                                   \
        KSLOT(p1_, p0_, Ta_.y, La_.y, 0, 0)                                   \
        KSLOT(p2_, p1_, Ta_.z, La_.z, 0, 0)                                   \
        KSLOT(p3_, p2_, Ta_.w, La_.w, 0, 0)                                   \
        KSLOT(p4_, p3_, Tb_.x, Lb_.x, 0, 0)                                   \
        KSLOT(p5_, p4_, Tb_.y, Lb_.y, 0, 0)                                   \
        KSLOT(p6_, p5_, Tb_.z, Lb_.z, 0, 0)                                   \
        KSLOT(0.f, p6_, Tb_.w, Lb_.w, 0, 1)                                   \
    }

/* ---------- Phase 1: vertical running windows into LDS (R12 champion) --- */
/* thread owns columns tid and tid+256; G=1 -> interior band, no guards     */
#define P1_INIT(G, C0, C1)                                                    \
    _Pragma("unroll")                                                         \
    for (int c = (C0); c < (C1); ++c) {                                       \
        const int y = y0 + c - PAD;                                           \
        float a0 = 0.f, a1 = 0.f;                                             \
        if ((G) || (unsigned)y < (unsigned)H) {                               \
            a0 = tcol[y * W]; a1 = tcol[y * W + 256];                         \
        }                                                                     \
        run0 += a0; run1 += a1;                                               \
    }

#define P1_SLIDE(G, J0, J1)                                                   \
    _Pragma("unroll")                                                         \
    for (int j = (J0); j < (J1); ++j) {                                       \
        vs[j][tid] = run0; vs[j][tid + 256] = run1;                           \
        if (j < BAND - 1) {                                                   \
            const int ye = y0 + j + PAD + 1, yl = y0 + j - PAD;               \
            float e0 = 0.f, e1 = 0.f, s0 = 0.f, s1 = 0.f;                     \
            if ((G) || (unsigned)ye < (unsigned)H) {                          \
                e0 = tcol[ye * W]; e1 = tcol[ye * W + 256];                   \
            }                                                                 \
            if ((G) || (unsigned)yl < (unsigned)H) {                          \
                s0 = tcol[yl * W]; s1 = tcol[yl * W + 256];                   \
            }                                                                 \
            run0 += e0 - s0; run1 += e1 - s1;                                 \
        }                                                                     \
    }

#define PHASE1(G)                                                             \
    P1_INIT(G, 0, 8)   __builtin_amdgcn_sched_barrier(0);                     \
    P1_INIT(G, 8, 16)  __builtin_amdgcn_sched_barrier(0);                     \
    P1_INIT(G, 16, 24) __builtin_amdgcn_sched_barrier(0);                     \
    P1_INIT(G, 24, 31) __builtin_amdgcn_sched_barrier(0);                     \
    P1_SLIDE(G, 0, 4)  __builtin_amdgcn_sched_barrier(0);                     \
    P1_SLIDE(G, 4, 8)

__global__ __launch_bounds__(256)
void wbce_band_kernel(const float* __restrict__ logits,
                      const float* __restrict__ targets,
                      float* __restrict__ partials) {
    __shared__ __align__(16) float vs[BAND][W];   /* 16 KB */

    const int tid  = threadIdx.x;
    const int lane = tid & 63;
    const int w    = tid >> 6;

    /* XCD-aware bijective swizzle: 256 consecutive blocks (4 images) per XCD */
    const int bid  = (int)blockIdx.x;
    const int sbid = (bid & (NXCD - 1)) * (NBLOCKS / NXCD) + (bid >> 3);

    const int img  = sbid >> 6;            /* sbid / NBANDS */
    const int band = sbid & (NBANDS - 1);
    const int y0   = band * BAND;
    const int x0   = lane * 8;

    const float* tb = targets + (size_t)img * H * W;
    const float* lb = logits  + (size_t)img * H * W;
    const float* tcol = tb + tid;

    /* ---- Phase 1: cooperative vertical 31-row windows -> LDS ---- */
    float run0 = 0.f, run1 = 0.f;
    if (y0 >= PAD && y0 + BAND + PAD - 1 < H) {
        PHASE1(1)
    } else {
        PHASE1(0)
    }
    __syncthreads();

    /* ---- Phase 2: horizontal window + fused weight/BCE (wave = 2 rows) ---- */
    const bool okm2 = lane >= 2, okm1 = lane >= 1;
    const bool okp1 = lane <= 62, okp2 = lane <= 61;
    float num = 0.f, den = 0.f;

    const int jw = w * 2;
    ROWPASS(jw)
    ROWPASS(jw + 1)

    /* ---- wave reduction, one partial pair per wave ---- */
    #pragma unroll
    for (int off = 32; off > 0; off >>= 1) {
        num += __shfl_down(num, off);
        den += __shfl_down(den, off);
    }
    if (lane == 0) {
        const int wid = sbid * 4 + w;
        partials[wid * 2]     = num;
        partials[wid * 2 + 1] = den;
    }
}

/* 8192 partial pairs -> scalar. Image i owns pairs [i*256, i*256+256). */
__global__ __launch_bounds__(1024)
void wbce_finalize_kernel(const float* __restrict__ partials,
                          float* __restrict__ out) {
    __shared__ float rsum[16];
    const int t = threadIdx.x;
    const int img = t >> 5;
    const int j = t & 31;
    const int base = img * 256;
    float num = 0.f, den = 0.f;
    #pragma unroll
    for (int k = 0; k < 8; ++k) {
        num += partials[(base + j + 32 * k) * 2];
        den += partials[(base + j + 32 * k) * 2 + 1];
    }
    #pragma unroll
    for (int off = 16; off > 0; off >>= 1) {
        num += __shfl_down(num, off, 32);
        den += __shfl_down(den, off, 32);
    }
    float ratio = 0.f;
    if ((t & 31) == 0) ratio = num / den;
    ratio += __shfl_down(ratio, 32);          /* lane0 += lane32 */
    const int lane = t & 63;
    const int wv = t >> 6;
    if (lane == 0) rsum[wv] = ratio;
    __syncthreads();
    if (t == 0) {
        float s = 0.f;
        #pragma unroll
        for (int i = 0; i < 16; ++i) s += rsum[i];
        out[0] = s / (float)BATCH;
    }
}

extern "C" void kernel_launch(void* const* d_in, const int* in_sizes, int n_in,
                              void* d_out, int out_size, void* d_ws, size_t ws_size,
                              hipStream_t stream) {
    const float* logits  = (const float*)d_in[0];
    const float* targets = (const float*)d_in[1];
    float* out = (float*)d_out;
    float* partials = (float*)d_ws;   /* NBLOCKS*4*2 floats = 64 KB */

    wbce_band_kernel<<<NBLOCKS, 256, 0, stream>>>(logits, targets, partials);
    wbce_finalize_kernel<<<1, 1024, 0, stream>>>(partials, out);
}